// Round 1
// baseline (296.531 us; speedup 1.0000x reference)
//
#include <hip/hip_runtime.h>

typedef short bf16x8 __attribute__((ext_vector_type(8)));
typedef float f32x4 __attribute__((ext_vector_type(4)));
typedef unsigned int u32;
typedef unsigned short u16;

#define NT 32
#define NB 4096
#define ND 32
#define NW 64

// Dopri5 tableau
#define A31 ((float)(3.0/40.0))
#define A32 ((float)(9.0/40.0))
#define A41 ((float)(44.0/45.0))
#define A42 ((float)(-56.0/15.0))
#define A43 ((float)(32.0/9.0))
#define A51 ((float)(19372.0/6561.0))
#define A52 ((float)(-25360.0/2187.0))
#define A53 ((float)(64448.0/6561.0))
#define A54 ((float)(-212.0/729.0))
#define A61 ((float)(9017.0/3168.0))
#define A62 ((float)(-355.0/33.0))
#define A63 ((float)(46732.0/5247.0))
#define A64 ((float)(49.0/176.0))
#define A65 ((float)(-5103.0/18656.0))
#define BB1 ((float)(35.0/384.0))
#define BB3 ((float)(500.0/1113.0))
#define BB4 ((float)(125.0/192.0))
#define BB5 ((float)(-2187.0/6784.0))
#define BB6 ((float)(11.0/84.0))

__device__ __forceinline__ u16 f2bf(float x) {
    u32 u = __float_as_uint(x);
    u = (u + 0x7FFFu + ((u >> 16) & 1u)) >> 16;   // RNE
    return (u16)u;
}
__device__ __forceinline__ u32 pack2(float a, float b) {
    return (u32)f2bf(a) | ((u32)f2bf(b) << 16);
}
__device__ __forceinline__ float sp(float x) {   // softplus, numerically stable
    return fmaxf(x, 0.0f) + __logf(1.0f + __expf(-fabsf(x)));
}

__global__ __launch_bounds__(256, 1)
void node_kernel(const float* __restrict__ ts, const float* __restrict__ y0,
                 const float* __restrict__ W1, const float* __restrict__ b1,
                 const float* __restrict__ W2, const float* __restrict__ b2,
                 const float* __restrict__ W3, const float* __restrict__ b3,
                 float* __restrict__ out)
{
    // y_stage bf16 [n][k] pairs, row stride 20 u32 (=40 shorts, 80B: 16B-aligned frags, 2-way banks)
    __shared__ __align__(16) u32 yls[16 * 20];
    // h activations bf16 [n][k], row stride 36 u32 (=72 shorts, 144B)
    __shared__ __align__(16) u32 h1ls[16 * 36];
    __shared__ __align__(16) u32 h2ls[16 * 36];
    // L3 partials fp32 [kc][n][m], row stride 36 floats (144B)
    __shared__ __align__(16) float pls[2 * 16 * 36];

    const int tid  = threadIdx.x;
    const int wv   = tid >> 6;       // wave 0..3
    const int lane = tid & 63;
    const int r16  = lane & 15;      // MFMA: A-row / B-col / D-col
    const int q    = lane >> 4;      // MFMA quad
    const int mt   = wv >> 1;        // L3 m-tile
    const int kc   = wv & 1;         // L3 k-chunk

    const int cn   = tid & 15;       // combine: batch col n
    const int cm2  = tid >> 4;       // combine: owns state dims 2*cm2, 2*cm2+1

    const int row0 = blockIdx.x * 16;

    // ---- weight A-fragments (bf16), biases ----
    bf16x8 a1, a2lo, a2hi, a3;
    {
        const float* p = W1 + (wv * 16 + r16) * ND + q * 8;
        #pragma unroll
        for (int e = 0; e < 8; ++e) a1[e] = (short)f2bf(p[e]);
    }
    {
        const float* p = W2 + (wv * 16 + r16) * NW + q * 8;
        #pragma unroll
        for (int e = 0; e < 8; ++e) a2lo[e] = (short)f2bf(p[e]);
        #pragma unroll
        for (int e = 0; e < 8; ++e) a2hi[e] = (short)f2bf(p[e + 32]);
    }
    {
        const float* p = W3 + (mt * 16 + r16) * NW + kc * 32 + q * 8;
        #pragma unroll
        for (int e = 0; e < 8; ++e) a3[e] = (short)f2bf(p[e]);
    }
    float bs1[4], bs2[4], bs3[4];
    #pragma unroll
    for (int j = 0; j < 4; ++j) {
        bs1[j] = b1[wv * 16 + q * 4 + j];
        bs2[j] = b2[wv * 16 + q * 4 + j];
        bs3[j] = (kc == 0) ? b3[mt * 16 + q * 4 + j] : 0.0f;
    }

    // ---- init state (thread-owned 2 elements) ----
    float yr0 = y0[(row0 + cn) * ND + 2 * cm2];
    float yr1 = y0[(row0 + cn) * ND + 2 * cm2 + 1];
    {
        float2 v; v.x = yr0; v.y = yr1;
        *(float2*)&out[(size_t)(row0 + cn) * ND + 2 * cm2] = v;   // ys[0] = y0
    }
    yls[cn * 20 + cm2] = pack2(yr0, yr1);

    const u16* yls16 = (const u16*)yls;
    const u16* h1s16 = (const u16*)h1ls;
    const u16* h2s16 = (const u16*)h2ls;

    auto evalf = [&](float& kA, float& kB) {
        __syncthreads();                                   // A: y_stage ready
        bf16x8 by = *(const bf16x8*)(yls16 + r16 * 40 + q * 8);
        f32x4 acc = {bs1[0], bs1[1], bs1[2], bs1[3]};
        acc = __builtin_amdgcn_mfma_f32_16x16x32_bf16(a1, by, acc, 0, 0, 0);
        h1ls[r16 * 36 + wv * 8 + q * 2]     = pack2(sp(acc[0]), sp(acc[1]));
        h1ls[r16 * 36 + wv * 8 + q * 2 + 1] = pack2(sp(acc[2]), sp(acc[3]));
        __syncthreads();                                   // B: h1 ready
        bf16x8 bh0 = *(const bf16x8*)(h1s16 + r16 * 72 + q * 8);
        bf16x8 bh1 = *(const bf16x8*)(h1s16 + r16 * 72 + 32 + q * 8);
        f32x4 ac2 = {bs2[0], bs2[1], bs2[2], bs2[3]};
        ac2 = __builtin_amdgcn_mfma_f32_16x16x32_bf16(a2lo, bh0, ac2, 0, 0, 0);
        ac2 = __builtin_amdgcn_mfma_f32_16x16x32_bf16(a2hi, bh1, ac2, 0, 0, 0);
        h2ls[r16 * 36 + wv * 8 + q * 2]     = pack2(sp(ac2[0]), sp(ac2[1]));
        h2ls[r16 * 36 + wv * 8 + q * 2 + 1] = pack2(sp(ac2[2]), sp(ac2[3]));
        __syncthreads();                                   // C: h2 ready
        bf16x8 bh2 = *(const bf16x8*)(h2s16 + r16 * 72 + kc * 32 + q * 8);
        f32x4 ac3 = {bs3[0], bs3[1], bs3[2], bs3[3]};
        ac3 = __builtin_amdgcn_mfma_f32_16x16x32_bf16(a3, bh2, ac3, 0, 0, 0);
        *(f32x4*)&pls[kc * 576 + r16 * 36 + mt * 16 + q * 4] = ac3;
        __syncthreads();                                   // D: partials ready
        float2 pa = *(const float2*)&pls[cn * 36 + 2 * cm2];
        float2 pb = *(const float2*)&pls[576 + cn * 36 + 2 * cm2];
        kA = pa.x + pb.x;
        kB = pa.y + pb.y;
    };

    #pragma unroll 1
    for (int iv = 0; iv < NT - 1; ++iv) {
        const float h = (ts[iv + 1] - ts[iv]) * 0.5f;      // K=2 substeps
        #pragma unroll 1
        for (int sub = 0; sub < 2; ++sub) {
            float k1a,k1b,k2a,k2b,k3a,k3b,k4a,k4b,k5a,k5b,k6a,k6b;
            evalf(k1a, k1b);
            yls[cn * 20 + cm2] = pack2(yr0 + h * (0.2f * k1a),
                                       yr1 + h * (0.2f * k1b));
            evalf(k2a, k2b);
            yls[cn * 20 + cm2] = pack2(yr0 + h * (A31 * k1a + A32 * k2a),
                                       yr1 + h * (A31 * k1b + A32 * k2b));
            evalf(k3a, k3b);
            yls[cn * 20 + cm2] = pack2(yr0 + h * (A41 * k1a + A42 * k2a + A43 * k3a),
                                       yr1 + h * (A41 * k1b + A42 * k2b + A43 * k3b));
            evalf(k4a, k4b);
            yls[cn * 20 + cm2] = pack2(yr0 + h * (A51 * k1a + A52 * k2a + A53 * k3a + A54 * k4a),
                                       yr1 + h * (A51 * k1b + A52 * k2b + A53 * k3b + A54 * k4b));
            evalf(k5a, k5b);
            yls[cn * 20 + cm2] = pack2(yr0 + h * (A61 * k1a + A62 * k2a + A63 * k3a + A64 * k4a + A65 * k5a),
                                       yr1 + h * (A61 * k1b + A62 * k2b + A63 * k3b + A64 * k4b + A65 * k5b));
            evalf(k6a, k6b);
            yr0 += h * (BB1 * k1a + BB3 * k3a + BB4 * k4a + BB5 * k5a + BB6 * k6a);
            yr1 += h * (BB1 * k1b + BB3 * k3b + BB4 * k4b + BB5 * k5b + BB6 * k6b);
            yls[cn * 20 + cm2] = pack2(yr0, yr1);
        }
        float2 v; v.x = yr0; v.y = yr1;
        *(float2*)&out[((size_t)(iv + 1) * NB + row0 + cn) * ND + 2 * cm2] = v;
    }

    if (blockIdx.x == 0 && tid == 0) {
        out[(size_t)NT * NB * ND] = 62.0f;   // num_steps = (T-1)*K, read back as f32
    }
}

extern "C" void kernel_launch(void* const* d_in, const int* in_sizes, int n_in,
                              void* d_out, int out_size, void* d_ws, size_t ws_size,
                              hipStream_t stream) {
    const float* ts = (const float*)d_in[0];
    const float* y0 = (const float*)d_in[1];
    const float* W1 = (const float*)d_in[2];
    const float* b1 = (const float*)d_in[3];
    const float* W2 = (const float*)d_in[4];
    const float* b2 = (const float*)d_in[5];
    const float* W3 = (const float*)d_in[6];
    const float* b3 = (const float*)d_in[7];
    float* out = (float*)d_out;

    node_kernel<<<dim3(NB / 16), dim3(256), 0, stream>>>(ts, y0, W1, b1, W2, b2, W3, b3, out);
}